// Round 14
// baseline (2226.907 us; speedup 1.0000x reference)
//
#include <hip/hip_runtime.h>

// TAMCaD_T fused attention-over-variables.
// q,k,v: (B=16, G=32, H=32, S=4096) fp32, s contiguous.
// Per (b,s): logits[g][f] = scale * sum_d q[g,d]k[f,d]; attn = softmax_f; x[g,d] = sum_f attn*v[f,d].
// Outputs (concat fp32): x (B,G*H,S) | attentions (B,G,G,S) | logits (B,G,G,S).
//
// Round-14: fused (split regressed, r13), ONE barrier, attn handoff via __shfl.
//  - Staging + QK + softmax = round 2 (best, 513 us).
//  - PV: attn[g][f] broadcast intra-wave with ds_bpermute of bf16-packed pairs
//    (src lane (f>>2)*8+sp) -- no attn LDS buffer, no 2nd/3rd barrier.
//  - PV in TWO d-half passes so peak live regs ~50 (r3/6/12: allocator gives
//    ~64 VGPR and spills anything fatter; r12 spill cost +2.6 GB traffic).
//  - LDS 64 KB (k+v only) -> 2 blocks/CU; waves drift freely after the single
//    barrier; resident blocks overlap stage bursts with compute.

constexpr int S_LEN = 4096;
constexpr int GG = 32;   // groups (q and kv)
constexpr int HH = 32;   // hidden dim (dk), n_heads = 1
constexpr int TS = 16;   // timesteps per block -> 64-B global segments
constexpr float SCALE = 0.17677669529663687f;  // 32^-0.5

__device__ __forceinline__ unsigned bf16pack(float a, float b) {
    // round-to-nearest-even bf16 pair in a u32 (lo = a, hi = b)
    unsigned ua = __float_as_uint(a);
    unsigned ub = __float_as_uint(b);
    ua = (ua + 0x7fffu + ((ua >> 16) & 1u)) >> 16;
    ub = (ub + 0x7fffu + ((ub >> 16) & 1u)) >> 16;
    return ua | (ub << 16);
}

__global__ __launch_bounds__(512, 4) void tamcad_fused(
    const float* __restrict__ q, const float* __restrict__ k,
    const float* __restrict__ v, float* __restrict__ x_out,
    float* __restrict__ attn_out, float* __restrict__ logit_out)
{
    // k/v: bf16 s-pairs, u32 word for (row, sp) at row*8 + (sp ^ (row&4)).
    // k rows rotated (d + f>>2)&31; v rows bit-rotated ((d&3)<<3)|(d>>2).
    __shared__ __align__(16) unsigned k_lds[GG * HH * TS / 2];  // 8192 u32 = 32 KB
    __shared__ __align__(16) unsigned v_lds[GG * HH * TS / 2];  // 32 KB

    // XCD-bijective swizzle (nwg = 4096, divisible by 8)
    const int nwg = gridDim.x;
    const int cpx = nwg >> 3;
    const int raw = blockIdx.x;
    const int logical = (raw & 7) * cpx + (raw >> 3);
    const int b  = logical >> 8;       // / (S/TS = 256)
    const int st = logical & 255;
    const int s0 = st * TS;

    const int tid = threadIdx.x;
    const int gt = tid >> 6;           // 0..7  g-tile (one per wave)
    const int ft = (tid >> 3) & 7;     // 0..7  f-tile (QK) / d-tile (PV)
    const int sp = tid & 7;            // 0..7  s-pair (2 timesteps each)

    const int baseB = b * (GG * HH);   // row base (rows of length S)
    const float* qb = q + (size_t)baseB * S_LEN + s0;
    const float* kb = k + (size_t)baseB * S_LEN + s0;
    const float* vb = v + (size_t)baseB * S_LEN + s0;

    // ---------------- stage k, v -> LDS bf16 (swizzled; round-2 layout) ----------------
    for (int r = tid; r < GG * HH; r += 512) {
        const int f = r >> 5, d = r & 31;
        const float4* ks = reinterpret_cast<const float4*>(kb + (size_t)r * S_LEN);
        const float4* vs = reinterpret_cast<const float4*>(vb + (size_t)r * S_LEN);
        float4 k0 = ks[0], k1 = ks[1], k2 = ks[2], k3 = ks[3];
        float4 v0 = vs[0], v1 = vs[1], v2 = vs[2], v3 = vs[3];
        uint4 kl, kh, vl, vh;
        kl.x = bf16pack(k0.x, k0.y); kl.y = bf16pack(k0.z, k0.w);
        kl.z = bf16pack(k1.x, k1.y); kl.w = bf16pack(k1.z, k1.w);
        kh.x = bf16pack(k2.x, k2.y); kh.y = bf16pack(k2.z, k2.w);
        kh.z = bf16pack(k3.x, k3.y); kh.w = bf16pack(k3.z, k3.w);
        vl.x = bf16pack(v0.x, v0.y); vl.y = bf16pack(v0.z, v0.w);
        vl.z = bf16pack(v1.x, v1.y); vl.w = bf16pack(v1.z, v1.w);
        vh.x = bf16pack(v2.x, v2.y); vh.y = bf16pack(v2.z, v2.w);
        vh.z = bf16pack(v3.x, v3.y); vh.w = bf16pack(v3.z, v3.w);
        const int rk = f * 32 + ((d + (f >> 2)) & 31);
        const int xk = rk & 4;
        *reinterpret_cast<uint4*>(&k_lds[rk * 8 + xk])       = kl;  // sp 0-3
        *reinterpret_cast<uint4*>(&k_lds[rk * 8 + (4 ^ xk)]) = kh;  // sp 4-7
        const int rv = f * 32 + (((d & 3) << 3) | (d >> 2));
        const int xv = rv & 4;
        *reinterpret_cast<uint4*>(&v_lds[rv * 8 + xv])       = vl;
        *reinterpret_cast<uint4*>(&v_lds[rv * 8 + (4 ^ xv)]) = vh;
    }
    __syncthreads();   // the ONLY barrier; k_lds/v_lds read-only from here

    // ---------------- QK^T: acc[4g][4f][2s] ----------------
    float acc[4][4][2];
    #pragma unroll
    for (int j = 0; j < 4; ++j)
        #pragma unroll
        for (int i = 0; i < 4; ++i) { acc[j][i][0] = 0.f; acc[j][i][1] = 0.f; }

    {
        const float* qrow[4];
        #pragma unroll
        for (int j = 0; j < 4; ++j)
            qrow[j] = qb + (size_t)((gt * 4 + j) * HH) * S_LEN + sp * 2;

        #pragma unroll 4
        for (int d = 0; d < HH; ++d) {
            float2 qv[4];
            #pragma unroll
            for (int j = 0; j < 4; ++j)
                qv[j] = *reinterpret_cast<const float2*>(qrow[j] + (size_t)d * S_LEN);
            const int dd = (d + ft) & 31;        // store rotation (f>>2 == ft)
            const int so = sp ^ (dd & 4);
            #pragma unroll
            for (int i = 0; i < 4; ++i) {
                const unsigned w = k_lds[((ft * 4 + i) * 32 + dd) * 8 + so];
                const float klo = __uint_as_float(w << 16);
                const float khi = __uint_as_float(w & 0xffff0000u);
                #pragma unroll
                for (int j = 0; j < 4; ++j) {
                    acc[j][i][0] = fmaf(qv[j].x, klo, acc[j][i][0]);
                    acc[j][i][1] = fmaf(qv[j].y, khi, acc[j][i][1]);
                }
            }
        }
    }
    #pragma unroll
    for (int j = 0; j < 4; ++j)
        #pragma unroll
        for (int i = 0; i < 4; ++i) { acc[j][i][0] *= SCALE; acc[j][i][1] *= SCALE; }

    // ---------------- softmax over f (4 local f x 8 ft lanes; intra-wave) ----------------
    float mx[4][2];
    #pragma unroll
    for (int j = 0; j < 4; ++j) {
        #pragma unroll
        for (int e = 0; e < 2; ++e) {
            float m = fmaxf(fmaxf(acc[j][0][e], acc[j][1][e]),
                            fmaxf(acc[j][2][e], acc[j][3][e]));
            m = fmaxf(m, __shfl_xor(m, 8));
            m = fmaxf(m, __shfl_xor(m, 16));
            m = fmaxf(m, __shfl_xor(m, 32));
            mx[j][e] = m;
        }
    }
    // store logits, overwrite acc in place with exp(acc - m)
    #pragma unroll
    for (int j = 0; j < 4; ++j) {
        const int g = gt * 4 + j;
        #pragma unroll
        for (int i = 0; i < 4; ++i) {
            const int f = ft * 4 + i;
            const size_t o = (size_t)(baseB + g * GG + f) * S_LEN + s0 + sp * 2;
            *reinterpret_cast<float2*>(logit_out + o) = make_float2(acc[j][i][0], acc[j][i][1]);
            acc[j][i][0] = __expf(acc[j][i][0] - mx[j][0]);
            acc[j][i][1] = __expf(acc[j][i][1] - mx[j][1]);
        }
    }
    float inv[4][2];
    #pragma unroll
    for (int j = 0; j < 4; ++j) {
        #pragma unroll
        for (int e = 0; e < 2; ++e) {
            float s = acc[j][0][e] + acc[j][1][e] + acc[j][2][e] + acc[j][3][e];
            s += __shfl_xor(s, 8);
            s += __shfl_xor(s, 16);
            s += __shfl_xor(s, 32);
            inv[j][e] = __builtin_amdgcn_rcpf(s);
        }
    }
    // attn: global store + bf16 pack into apack[i][j] (acc dead afterwards)
    unsigned apack[4][4];
    #pragma unroll
    for (int j = 0; j < 4; ++j) {
        const int g = gt * 4 + j;
        #pragma unroll
        for (int i = 0; i < 4; ++i) {
            const int f = ft * 4 + i;
            const float a0 = acc[j][i][0] * inv[j][0];
            const float a1 = acc[j][i][1] * inv[j][1];
            const size_t o = (size_t)(baseB + g * GG + f) * S_LEN + s0 + sp * 2;
            *reinterpret_cast<float2*>(attn_out + o) = make_float2(a0, a1);
            apack[i][j] = bf16pack(a0, a1);
        }
    }

    // ---------------- PV via intra-wave shfl broadcast, two d-half passes ----------------
    // attn[g=gt*4+j][f] lives as apack[f&3][j] on lane (f>>2)*8+sp (wave-local).
    // Each pass: xacc[4g][2d][2s] (16 regs) -> peak live ~50, no spill.
    const int dt = ft;
    const int sov = sp ^ (dt & 4);   // v-row XOR: (f*32 + i*8 + dt)&4 == dt&4
#define PV_PASS(I0)                                                            \
    {                                                                          \
        float xacc[4][2][2];                                                   \
        _Pragma("unroll")                                                      \
        for (int j = 0; j < 4; ++j) {                                          \
            xacc[j][0][0] = 0.f; xacc[j][0][1] = 0.f;                          \
            xacc[j][1][0] = 0.f; xacc[j][1][1] = 0.f;                          \
        }                                                                      \
        _Pragma("unroll")                                                      \
        for (int f = 0; f < GG; ++f) {                                         \
            const int srcl = ((f >> 2) << 3) + sp;                             \
            unsigned aw[4];                                                    \
            _Pragma("unroll")                                                  \
            for (int j = 0; j < 4; ++j)                                        \
                aw[j] = (unsigned)__shfl((int)apack[f & 3][j], srcl);          \
            _Pragma("unroll")                                                  \
            for (int ih = 0; ih < 2; ++ih) {                                   \
                const int i = (I0) + ih;                                       \
                const unsigned wv = v_lds[(f * 32 + i * 8 + dt) * 8 + sov];    \
                const float vlo = __uint_as_float(wv << 16);                   \
                const float vhi = __uint_as_float(wv & 0xffff0000u);           \
                _Pragma("unroll")                                              \
                for (int j = 0; j < 4; ++j) {                                  \
                    const float alo = __uint_as_float(aw[j] << 16);            \
                    const float ahi = __uint_as_float(aw[j] & 0xffff0000u);    \
                    xacc[j][ih][0] = fmaf(alo, vlo, xacc[j][ih][0]);           \
                    xacc[j][ih][1] = fmaf(ahi, vhi, xacc[j][ih][1]);           \
                }                                                              \
            }                                                                  \
        }                                                                      \
        _Pragma("unroll")                                                      \
        for (int j = 0; j < 4; ++j) {                                          \
            const int g = gt * 4 + j;                                          \
            _Pragma("unroll")                                                  \
            for (int ih = 0; ih < 2; ++ih) {                                   \
                const int d = dt * 4 + (I0) + ih;                              \
                const size_t o = (size_t)(baseB + g * HH + d) * S_LEN          \
                                 + s0 + sp * 2;                                \
                *reinterpret_cast<float2*>(x_out + o) =                        \
                    make_float2(xacc[j][ih][0], xacc[j][ih][1]);               \
            }                                                                  \
        }                                                                      \
    }
    PV_PASS(0)   // d = dt*4 + {0,1}
    PV_PASS(2)   // d = dt*4 + {2,3}
#undef PV_PASS
}

extern "C" void kernel_launch(void* const* d_in, const int* in_sizes, int n_in,
                              void* d_out, int out_size, void* d_ws, size_t ws_size,
                              hipStream_t stream) {
    const float* q = (const float*)d_in[0];
    const float* k = (const float*)d_in[1];
    const float* v = (const float*)d_in[2];
    float* out = (float*)d_out;
    const int n = in_sizes[0];                  // B*G*H*S = 67108864
    const int B = n / (GG * HH * S_LEN);        // 16
    float* x_out     = out;
    float* attn_out  = out + (size_t)n;
    float* logit_out = out + (size_t)2 * n;
    const int nwg = B * (S_LEN / TS);           // 4096
    tamcad_fused<<<dim3(nwg), dim3(512), 0, stream>>>(q, k, v, x_out, attn_out, logit_out);
}

// Round 15
// 525.789 us; speedup vs baseline: 4.2354x; 4.2354x over previous
//
#include <hip/hip_runtime.h>

// TAMCaD_T fused attention-over-variables.
// q,k,v: (B=16, G=32, H=32, S=4096) fp32, s contiguous.
// Per (b,s): logits[g][f] = scale * sum_d q[g,d]k[f,d]; attn = softmax_f; x[g,d] = sum_f attn*v[f,d].
// Outputs (concat fp32): x (B,G*H,S) | attentions (B,G,G,S) | logits (B,G,G,S).
//
// Round-15 = round-8 structure with __launch_bounds__(512,2).
// ALLOCATOR LAW (4 data points, r3/r6/r12/r14): hipcc caps VGPR at 256/N for
// launch_bounds 2nd arg N, and SPILLS rather than exceed it. (512,4)->64 cap
// killed every restructure. With 64-80 KB LDS the occupancy limit is already
// 2 blocks/CU = 4 waves/SIMD, which permits 128 VGPR -- so N=2 raises the cap
// to exactly what occupancy allows, for free.
//  - Staging + QK + softmax identical to round 2 (LDS-staged bf16 k/v, TS=16).
//  - attn redistribution INTRA-WAVE: per-wave 2-KB double-buffered LDS slice,
//    written+read by the same wave (DS ops in-order), NO barrier.
//  - Exactly ONE __syncthreads (after k/v staging). Waves drift freely after;
//    next block's staging overlaps this block's PV.
//  - Structure verified correct in r12 (passed, absmax 0.031; slow only due to
//    the 64-VGPR spill this round removes).

constexpr int S_LEN = 4096;
constexpr int GG = 32;   // groups (q and kv)
constexpr int HH = 32;   // hidden dim (dk), n_heads = 1
constexpr int TS = 16;   // timesteps per block -> 64-B global segments
constexpr float SCALE = 0.17677669529663687f;  // 32^-0.5

__device__ __forceinline__ unsigned bf16pack(float a, float b) {
    // round-to-nearest-even bf16 pair in a u32 (lo = a, hi = b)
    unsigned ua = __float_as_uint(a);
    unsigned ub = __float_as_uint(b);
    ua = (ua + 0x7fffu + ((ua >> 16) & 1u)) >> 16;
    ub = (ub + 0x7fffu + ((ub >> 16) & 1u)) >> 16;
    return ua | (ub << 16);
}

__global__ __launch_bounds__(512, 2) void tamcad_fused(
    const float* __restrict__ q, const float* __restrict__ k,
    const float* __restrict__ v, float* __restrict__ x_out,
    float* __restrict__ attn_out, float* __restrict__ logit_out)
{
    // k/v: bf16 s-pairs, u32 word for (row, sp) at row*8 + (sp ^ (row&4)).
    // k rows rotated (d + f>>2)&31; v rows bit-rotated ((d&3)<<3)|(d>>2).
    __shared__ __align__(16) unsigned k_lds[GG * HH * TS / 2];  // 8192 u32 = 32 KB
    __shared__ __align__(16) unsigned v_lds[GG * HH * TS / 2];  // 32 KB
    // per-wave attn transpose scratch: 8 waves x 512 u32 (two 256-u32 slots) = 16 KB
    __shared__ __align__(16) unsigned a_lds[8 * 512];

    // XCD-bijective swizzle (nwg = 4096, divisible by 8)
    const int nwg = gridDim.x;
    const int cpx = nwg >> 3;
    const int raw = blockIdx.x;
    const int logical = (raw & 7) * cpx + (raw >> 3);
    const int b  = logical >> 8;       // / (S/TS = 256)
    const int st = logical & 255;
    const int s0 = st * TS;

    const int tid = threadIdx.x;
    const int gt = tid >> 6;           // 0..7  g-tile (one per wave)
    const int ft = (tid >> 3) & 7;     // 0..7  f-tile (QK) / d-tile (PV)
    const int sp = tid & 7;            // 0..7  s-pair (2 timesteps each)

    const int baseB = b * (GG * HH);   // row base (rows of length S)
    const float* qb = q + (size_t)baseB * S_LEN + s0;
    const float* kb = k + (size_t)baseB * S_LEN + s0;
    const float* vb = v + (size_t)baseB * S_LEN + s0;

    // ---------------- stage k, v -> LDS bf16 (swizzled; round-2 layout) ----------------
    for (int r = tid; r < GG * HH; r += 512) {
        const int f = r >> 5, d = r & 31;
        const float4* ks = reinterpret_cast<const float4*>(kb + (size_t)r * S_LEN);
        const float4* vs = reinterpret_cast<const float4*>(vb + (size_t)r * S_LEN);
        float4 k0 = ks[0], k1 = ks[1], k2 = ks[2], k3 = ks[3];
        float4 v0 = vs[0], v1 = vs[1], v2 = vs[2], v3 = vs[3];
        uint4 kl, kh, vl, vh;
        kl.x = bf16pack(k0.x, k0.y); kl.y = bf16pack(k0.z, k0.w);
        kl.z = bf16pack(k1.x, k1.y); kl.w = bf16pack(k1.z, k1.w);
        kh.x = bf16pack(k2.x, k2.y); kh.y = bf16pack(k2.z, k2.w);
        kh.z = bf16pack(k3.x, k3.y); kh.w = bf16pack(k3.z, k3.w);
        vl.x = bf16pack(v0.x, v0.y); vl.y = bf16pack(v0.z, v0.w);
        vl.z = bf16pack(v1.x, v1.y); vl.w = bf16pack(v1.z, v1.w);
        vh.x = bf16pack(v2.x, v2.y); vh.y = bf16pack(v2.z, v2.w);
        vh.z = bf16pack(v3.x, v3.y); vh.w = bf16pack(v3.z, v3.w);
        const int rk = f * 32 + ((d + (f >> 2)) & 31);
        const int xk = rk & 4;
        *reinterpret_cast<uint4*>(&k_lds[rk * 8 + xk])       = kl;  // sp 0-3
        *reinterpret_cast<uint4*>(&k_lds[rk * 8 + (4 ^ xk)]) = kh;  // sp 4-7
        const int rv = f * 32 + (((d & 3) << 3) | (d >> 2));
        const int xv = rv & 4;
        *reinterpret_cast<uint4*>(&v_lds[rv * 8 + xv])       = vl;
        *reinterpret_cast<uint4*>(&v_lds[rv * 8 + (4 ^ xv)]) = vh;
    }
    __syncthreads();   // the ONLY barrier; k_lds/v_lds read-only from here

    // ---------------- QK^T: acc[4g][4f][2s] ----------------
    float acc[4][4][2];
    #pragma unroll
    for (int j = 0; j < 4; ++j)
        #pragma unroll
        for (int i = 0; i < 4; ++i) { acc[j][i][0] = 0.f; acc[j][i][1] = 0.f; }

    {
        const float* qrow[4];
        #pragma unroll
        for (int j = 0; j < 4; ++j)
            qrow[j] = qb + (size_t)((gt * 4 + j) * HH) * S_LEN + sp * 2;

        #pragma unroll 4
        for (int d = 0; d < HH; ++d) {
            float2 qv[4];
            #pragma unroll
            for (int j = 0; j < 4; ++j)
                qv[j] = *reinterpret_cast<const float2*>(qrow[j] + (size_t)d * S_LEN);
            const int dd = (d + ft) & 31;        // store rotation (f>>2 == ft)
            const int so = sp ^ (dd & 4);
            #pragma unroll
            for (int i = 0; i < 4; ++i) {
                const unsigned w = k_lds[((ft * 4 + i) * 32 + dd) * 8 + so];
                const float klo = __uint_as_float(w << 16);
                const float khi = __uint_as_float(w & 0xffff0000u);
                #pragma unroll
                for (int j = 0; j < 4; ++j) {
                    acc[j][i][0] = fmaf(qv[j].x, klo, acc[j][i][0]);
                    acc[j][i][1] = fmaf(qv[j].y, khi, acc[j][i][1]);
                }
            }
        }
    }
    #pragma unroll
    for (int j = 0; j < 4; ++j)
        #pragma unroll
        for (int i = 0; i < 4; ++i) { acc[j][i][0] *= SCALE; acc[j][i][1] *= SCALE; }

    // ---------------- softmax over f (4 local f x 8 ft lanes; intra-wave) ----------------
    float mx[4][2];
    #pragma unroll
    for (int j = 0; j < 4; ++j) {
        #pragma unroll
        for (int e = 0; e < 2; ++e) {
            float m = fmaxf(fmaxf(acc[j][0][e], acc[j][1][e]),
                            fmaxf(acc[j][2][e], acc[j][3][e]));
            m = fmaxf(m, __shfl_xor(m, 8));
            m = fmaxf(m, __shfl_xor(m, 16));
            m = fmaxf(m, __shfl_xor(m, 32));
            mx[j][e] = m;
        }
    }
    // store logits, overwrite acc in place with exp(acc - m)
    #pragma unroll
    for (int j = 0; j < 4; ++j) {
        const int g = gt * 4 + j;
        #pragma unroll
        for (int i = 0; i < 4; ++i) {
            const int f = ft * 4 + i;
            const size_t o = (size_t)(baseB + g * GG + f) * S_LEN + s0 + sp * 2;
            *reinterpret_cast<float2*>(logit_out + o) = make_float2(acc[j][i][0], acc[j][i][1]);
            acc[j][i][0] = __expf(acc[j][i][0] - mx[j][0]);
            acc[j][i][1] = __expf(acc[j][i][1] - mx[j][1]);
        }
    }
    float inv[4][2];
    #pragma unroll
    for (int j = 0; j < 4; ++j) {
        #pragma unroll
        for (int e = 0; e < 2; ++e) {
            float s = acc[j][0][e] + acc[j][1][e] + acc[j][2][e] + acc[j][3][e];
            s += __shfl_xor(s, 8);
            s += __shfl_xor(s, 16);
            s += __shfl_xor(s, 32);
            inv[j][e] = __builtin_amdgcn_rcpf(s);
        }
    }
    // attn: global store + bf16 pack (apack[i][j]; chunk i holds f = 4*ft + i)
    unsigned apack[4][4];
    #pragma unroll
    for (int j = 0; j < 4; ++j) {
        const int g = gt * 4 + j;
        #pragma unroll
        for (int i = 0; i < 4; ++i) {
            const int f = ft * 4 + i;
            const float a0 = acc[j][i][0] * inv[j][0];
            const float a1 = acc[j][i][1] * inv[j][1];
            const size_t o = (size_t)(baseB + g * GG + f) * S_LEN + s0 + sp * 2;
            *reinterpret_cast<float2*>(attn_out + o) = make_float2(a0, a1);
            apack[i][j] = bf16pack(a0, a1);
        }
    }

    // ---------------- PV via per-wave chunked transpose (NO barrier) ----------------
    // chunk fc = {f : f mod 4 == fc}; slot (fc&1) of this wave's 512-u32 slice.
    // write: lane (ft,sp) -> uint4 at (ft*8+sp)*4 (contiguous b128, conflict-free).
    // read:  slot[(t*8+sp)*4] -> f = 4t+fc; broadcast over dt, 32-bank over sp.
    unsigned* const slice = &a_lds[gt * 512];
    const int wsl = (ft * 8 + sp) * 4;
    {
        uint4 w;
        w.x = apack[0][0]; w.y = apack[0][1]; w.z = apack[0][2]; w.w = apack[0][3];
        *reinterpret_cast<uint4*>(&slice[wsl]) = w;   // chunk 0 -> slot 0
    }

    float xacc[4][4][2];
    #pragma unroll
    for (int j = 0; j < 4; ++j)
        #pragma unroll
        for (int i = 0; i < 4; ++i) { xacc[j][i][0] = 0.f; xacc[j][i][1] = 0.f; }

    const int dt = ft;
    const int sov = sp ^ (dt & 4);   // v-row XOR: rv&4 == dt&4
    #pragma unroll
    for (int fc = 0; fc < 4; ++fc) {
        // write next chunk into the other slot (issued before this chunk's math;
        // same-wave DS ops are in-order, so no hazard with slot (fc&1) reads)
        if (fc < 3) {
            uint4 w;
            w.x = apack[fc + 1][0]; w.y = apack[fc + 1][1];
            w.z = apack[fc + 1][2]; w.w = apack[fc + 1][3];
            *reinterpret_cast<uint4*>(&slice[((fc + 1) & 1) * 256 + wsl]) = w;
        }
        #pragma unroll
        for (int t = 0; t < 8; ++t) {
            const int f = t * 4 + fc;
            const uint4 wa = *reinterpret_cast<const uint4*>(
                &slice[(fc & 1) * 256 + (t * 8 + sp) * 4]);
            float alo[4], ahi[4];
            alo[0] = __uint_as_float(wa.x << 16); ahi[0] = __uint_as_float(wa.x & 0xffff0000u);
            alo[1] = __uint_as_float(wa.y << 16); ahi[1] = __uint_as_float(wa.y & 0xffff0000u);
            alo[2] = __uint_as_float(wa.z << 16); ahi[2] = __uint_as_float(wa.z & 0xffff0000u);
            alo[3] = __uint_as_float(wa.w << 16); ahi[3] = __uint_as_float(wa.w & 0xffff0000u);
            #pragma unroll
            for (int i = 0; i < 4; ++i) {
                // d = dt*4+i stored at pi(d) = i*8 + dt
                const unsigned wv = v_lds[(f * 32 + i * 8 + dt) * 8 + sov];
                const float vlo = __uint_as_float(wv << 16);
                const float vhi = __uint_as_float(wv & 0xffff0000u);
                #pragma unroll
                for (int j = 0; j < 4; ++j) {
                    xacc[j][i][0] = fmaf(alo[j], vlo, xacc[j][i][0]);
                    xacc[j][i][1] = fmaf(ahi[j], vhi, xacc[j][i][1]);
                }
            }
        }
    }
    // store x: x[b, g*32+d, s]
    #pragma unroll
    for (int j = 0; j < 4; ++j) {
        const int g = gt * 4 + j;
        #pragma unroll
        for (int i = 0; i < 4; ++i) {
            const int d = dt * 4 + i;
            const size_t o = (size_t)(baseB + g * HH + d) * S_LEN + s0 + sp * 2;
            *reinterpret_cast<float2*>(x_out + o) = make_float2(xacc[j][i][0], xacc[j][i][1]);
        }
    }
}

extern "C" void kernel_launch(void* const* d_in, const int* in_sizes, int n_in,
                              void* d_out, int out_size, void* d_ws, size_t ws_size,
                              hipStream_t stream) {
    const float* q = (const float*)d_in[0];
    const float* k = (const float*)d_in[1];
    const float* v = (const float*)d_in[2];
    float* out = (float*)d_out;
    const int n = in_sizes[0];                  // B*G*H*S = 67108864
    const int B = n / (GG * HH * S_LEN);        // 16
    float* x_out     = out;
    float* attn_out  = out + (size_t)n;
    float* logit_out = out + (size_t)2 * n;
    const int nwg = B * (S_LEN / TS);           // 4096
    tamcad_fused<<<dim3(nwg), dim3(512), 0, stream>>>(q, k, v, x_out, attn_out, logit_out);
}